// Round 21
// baseline (123.708 us; speedup 1.0000x reference)
//
#include <hip/hip_runtime.h>
#include <type_traits>

#define DI __device__ __forceinline__

typedef __attribute__((ext_vector_type(8))) __bf16 vbf8;
typedef __attribute__((ext_vector_type(8))) short  vs8;
typedef __attribute__((ext_vector_type(4))) float  f4;
typedef __attribute__((ext_vector_type(4))) unsigned int u32x4;

static constexpr int BB   = 2;
static constexpr int C    = 256;
static constexpr int NN   = 4096;   // H*W*D
static constexpr int HID  = 512;
static constexpr int QKVR = 1536;

// ---------- bf16 helpers ----------
static DI unsigned short f2bf(float f) {   // round-to-nearest-even
  unsigned int u = __builtin_bit_cast(unsigned int, f);
  u += 0x7fffu + ((u >> 16) & 1u);
  return (unsigned short)(u >> 16);
}
static DI unsigned int cvtpk(float lo, float hi) {  // 2xf32 -> packed bf16 (RNE)
  unsigned int r;
  asm("v_cvt_pk_bf16_f32 %0, %1, %2" : "=v"(r) : "v"(lo), "v"(hi));
  return r;
}
static DI float EXP2(float x) {            // raw v_exp_f32: 2^x, 1 trans op
  float r;
  asm("v_exp_f32 %0, %1" : "=v"(r) : "v"(x));
  return r;
}

// ---------- MFMA wrapper robust to builtin signature (v8bf16 vs v8i16) ----------
template <typename V>
static DI auto mfma_sel(V a, V b, f4 c, int)
    -> decltype(__builtin_amdgcn_mfma_f32_16x16x32_bf16(a, b, c, 0, 0, 0)) {
  return __builtin_amdgcn_mfma_f32_16x16x32_bf16(a, b, c, 0, 0, 0);
}
template <typename V>
static DI f4 mfma_sel(V a, V b, f4 c, long) {
  return __builtin_amdgcn_mfma_f32_16x16x32_bf16(
      __builtin_bit_cast(vs8, a), __builtin_bit_cast(vs8, b), c, 0, 0, 0);
}
static DI f4 MFMA(vs8 a, vs8 b, f4 c) {
  return mfma_sel(__builtin_bit_cast(vbf8, a), __builtin_bit_cast(vbf8, b), c, 0);
}

// ---------- async global->LDS, 16B per lane ----------
static DI void gll16(const unsigned short* g, unsigned short* l) {
  __builtin_amdgcn_global_load_lds(
      (const __attribute__((address_space(1))) unsigned int*)g,
      (__attribute__((address_space(3))) unsigned int*)l, 16, 0, 0);
}

// ---------- K0: cast weights to bf16 (fold g into w_qkv columns) ----------
__global__ void k_prep(const float* __restrict__ wqkv, const float* __restrict__ g,
                       const float* __restrict__ wout,
                       unsigned short* __restrict__ wg, unsigned short* __restrict__ wo) {
  int i = blockIdx.x * 256 + threadIdx.x;
  if (i < QKVR * C) wg[i] = f2bf(wqkv[i] * g[i & (C - 1)]);
  if (i < C * HID)  wo[i] = f2bf(wout[i]);
}

// ---------- K1: normalize x once, emit bf16 fragment-major tiles ----------
// xn[((b*64+bn)*32 + g)*512 + n*8 + i] = bf16(x[b][c=g*8+i][n0+n] * inv[n])
// (single rounding: f32 scaled before conversion). This is the exact layout
// k_qkv's gll16 staging + B-fragment reads consume conflict-free.
__global__ __launch_bounds__(256) void k_xn(const float* __restrict__ x,
                                            unsigned short* __restrict__ xn) {
  __shared__ float xsf[64 * 257];   // stride 257: write lanes hit distinct banks
  __shared__ float ps[4][64];
  __shared__ float inv[64];
  const int bn = blockIdx.x & 63, b = blockIdx.x >> 6;
  const int n0 = bn * 64;
  const int tid = threadIdx.x;
  const int nl = tid & 63, cb = tid >> 6;
  {
    const float* xp = x + (size_t)b * C * NN + n0 + nl;
    float s = 0.f;
    #pragma unroll 8
    for (int k = 0; k < 64; ++k) {
      int c = cb * 64 + k;
      float v = xp[(size_t)c * NN];
      s += v * v;
      xsf[nl * 257 + c] = v;
    }
    ps[cb][nl] = s;
  }
  __syncthreads();
  if (tid < 64) {
    float t4 = ps[0][tid] + ps[1][tid] + ps[2][tid] + ps[3][tid];
    inv[tid] = 16.0f / fmaxf(sqrtf(t4), 1e-12f);
  }
  __syncthreads();
  unsigned short* out = xn + (size_t)(b * 64 + bn) * 32 * 512;
  const float s = inv[nl];
  #pragma unroll
  for (int t = 0; t < 8; ++t) {
    const int g = cb * 8 + t;
    const float* src = &xsf[nl * 257 + g * 8];
    u32x4 pk;
    pk[0] = cvtpk(src[0] * s, src[1] * s);
    pk[1] = cvtpk(src[2] * s, src[3] * s);
    pk[2] = cvtpk(src[4] * s, src[5] * s);
    pk[3] = cvtpk(src[6] * s, src[7] * s);
    *(u32x4*)(&out[(size_t)g * 512 + nl * 8]) = pk;   // coalesced 1KB per group
  }
}

// ---------- K2: QKV projection GEMM (o-tile 256, n-tile 64) over pre-normalized xn ----------
// Stage the whole 64n x 256c bf16 tile (32 KB) once via gll16 (fragment-major, linear
// LDS), one barrier, K=256 MFMA loop. Norm already folded into xn; only q-scale left.
// V stored j-PERMUTED within each 64-block (sigma as before) for k_attn's direct pb pack.
__global__ __launch_bounds__(256) void k_qkv(const unsigned short* __restrict__ xn,
    const unsigned short* __restrict__ wg,
    unsigned short* __restrict__ qo, unsigned short* __restrict__ ko,
    unsigned short* __restrict__ vo) {
  __shared__ unsigned short xs[32 * 512];   // 32 KB, groups g of [64 n][8 c]
  const int bo = blockIdx.x % 6;
  const int bn = (blockIdx.x / 6) & 63;
  const int b  = blockIdx.x / 384;
  const int o0 = bo * 256, n0 = bn * 64;
  const int tid = threadIdx.x, wave = tid >> 6, lane = tid & 63;
  const int lr = lane & 15, lg = lane >> 4;
  {
    const unsigned short* src = xn + (size_t)(b * 64 + bn) * 32 * 512;
    #pragma unroll
    for (int p = 0; p < 8; ++p) {
      const int g = wave * 8 + p;
      gll16(src + (size_t)g * 512 + lane * 8, &xs[g * 512]);
    }
  }
  asm volatile("s_waitcnt vmcnt(0)");
  __syncthreads();
  const int orow = o0 + wave * 64;          // 64 rows per wave = 4 sub-tiles of 16
  f4 acc[4][4];
  #pragma unroll
  for (int om = 0; om < 4; ++om)
    #pragma unroll
    for (int nc = 0; nc < 4; ++nc) acc[om][nc] = f4{0.f, 0.f, 0.f, 0.f};
  const unsigned short* wpb = wg + (size_t)(orow + lr) * C + lg * 8;
  #pragma unroll
  for (int c0 = 0; c0 < C; c0 += 32) {
    vs8 bfv[4];
    #pragma unroll
    for (int nc = 0; nc < 4; ++nc)
      bfv[nc] = *(const vs8*)(&xs[((c0 >> 3) + lg) * 512 + (nc * 16 + lr) * 8]);
    #pragma unroll
    for (int om = 0; om < 4; ++om) {
      vs8 af = *(const vs8*)(wpb + (size_t)om * 16 * C + c0);
      #pragma unroll
      for (int nc = 0; nc < 4; ++nc) acc[om][nc] = MFMA(af, bfv[nc], acc[om][nc]);
    }
  }
  #pragma unroll
  for (int om = 0; om < 4; ++om) {
    const int om_row = orow + om * 16;
    const int otype = om_row >> 9;        // 0=q 1=k 2=v
    const int head  = (om_row >> 6) & 7;
    const int bh    = b * 8 + head;
    const int dbase = (om_row & 63) + lg * 4;
    const float s = (otype == 0) ? 0.125f * 1.44269504088896f : 1.0f; // dh^-0.5 * log2(e)
    #pragma unroll
    for (int nc = 0; nc < 4; ++nc) {
      const int n = n0 + nc * 16 + lr;
      if (otype < 2) {                    // q,k: [bh][n][64]
        unsigned short* dst = (otype == 0 ? qo : ko) + ((size_t)bh * NN + n) * 64 + dbase;
        unsigned int lo = cvtpk(acc[om][nc][0] * s, acc[om][nc][1] * s);
        unsigned int hi = cvtpk(acc[om][nc][2] * s, acc[om][nc][3] * s);
        *(unsigned long long*)dst = ((unsigned long long)hi << 32) | lo;
      } else {                            // v transposed + j-permuted: [bh][64][n_perm]
        // o = nc*16+lr; stored pos = kj*32 + (lr>>2)*8 + (nc&1)*4 + (lr&3), kj=nc>>1
        const int np = n0 + ((nc >> 1) << 5) + ((lr >> 2) << 3) + ((nc & 1) << 2) + (lr & 3);
        #pragma unroll
        for (int r = 0; r < 4; ++r)
          vo[((size_t)bh * 64 + dbase + r) * NN + np] = f2bf(acc[om][nc][r] * s);
      }
    }
  }
}

// ---------- K3: flash attention, v13 body (permuted-V direct pb packing) ----------
// 4 waves/block, 32 q/wave, KVBLK=64, K+V double-buffered in LDS (32 KB/block).
// No max-tracking (S hard-bounded). l via ones-row MFMA.
// __launch_bounds__(256,4): 64-reg budget (56 measured). NEVER min-waves 8 (32-reg spill).
__global__ __launch_bounds__(256, 4) void k_attn(const unsigned short* __restrict__ qq,
    const unsigned short* __restrict__ kk, const unsigned short* __restrict__ vv,
    unsigned short* __restrict__ ou) {
  __shared__ unsigned short stg[2][8192];      // [buf][ K 8 groups*512 | V 8 groups*512 ]
  constexpr int JCH = NN / 64;
  const int bid = blockIdx.x;
  const int swz = (bid & 7) * 64 + (bid >> 3); // XCD-aware, bijective (512 % 8 == 0)
  const int qt  = swz & 31;
  const int bh  = swz >> 5;
  const int tid = threadIdx.x, wave = tid >> 6, lane = tid & 63;
  const int lr = lane & 15, lg = lane >> 4;
  const int qbase = qt * 128 + wave * 32;
  const unsigned short* kb = kk + (size_t)bh * NN * 64;   // [n][64]
  const unsigned short* vb = vv + (size_t)bh * 64 * NN;   // [64][n_perm]
  vs8 qf[2][2];
  #pragma unroll
  for (int qn = 0; qn < 2; ++qn)
    #pragma unroll
    for (int kd = 0; kd < 2; ++kd)
      qf[qn][kd] = *(const vs8*)(qq + ((size_t)bh * NN + qbase + qn * 16 + lr) * 64 + kd * 32 + lg * 8);
  const vs8 onesf = {0x3F80, 0x3F80, 0x3F80, 0x3F80, 0x3F80, 0x3F80, 0x3F80, 0x3F80};
  const f4 zero4 = {0.f, 0.f, 0.f, 0.f};
  f4 oacc[4][2] = { { {0,0,0,0},{0,0,0,0} }, { {0,0,0,0},{0,0,0,0} },
                    { {0,0,0,0},{0,0,0,0} }, { {0,0,0,0},{0,0,0,0} } };
  f4 lacc[2] = { {0,0,0,0}, {0,0,0,0} };

  auto stage = [&](int j0, int buf) {
    #pragma unroll
    for (int p = 0; p < 2; ++p) {
      const int g  = wave * 2 + p;
      const int jt = g >> 1, kd = g & 1;     // K group
      gll16(kb + (size_t)(j0 + jt * 16 + lr) * 64 + kd * 32 + lg * 8,
            &stg[buf][g * 512]);
      const int dt = g >> 1, kj = g & 1;     // V group (global already j-permuted)
      gll16(vb + (size_t)(dt * 16 + lr) * NN + j0 + kj * 32 + lg * 8,
            &stg[buf][4096 + g * 512]);
    }
  };

  stage(0, 0);
  asm volatile("s_waitcnt vmcnt(0)");
  __syncthreads();

  for (int t = 0; t < JCH; ++t) {
    const int cur = t & 1;
    if (t + 1 < JCH) stage((t + 1) * 64, cur ^ 1);
    const unsigned short* sbk = stg[cur];
    const unsigned short* sbv = stg[cur] + 4096;
    // --- S^T = K Q^T : first MFMA uses loop-invariant zero C ---
    f4 s[4][2];
    __builtin_amdgcn_s_setprio(1);
    #pragma unroll
    for (int jt = 0; jt < 4; ++jt) {
      vs8 k0 = *(const vs8*)(sbk + (jt * 2 + 0) * 512 + lane * 8);
      vs8 k1 = *(const vs8*)(sbk + (jt * 2 + 1) * 512 + lane * 8);
      #pragma unroll
      for (int qn = 0; qn < 2; ++qn) {
        s[jt][qn] = MFMA(k0, qf[qn][0], zero4);
        s[jt][qn] = MFMA(k1, qf[qn][1], s[jt][qn]);
      }
    }
    __builtin_amdgcn_s_setprio(0);
    // --- P = 2^S, packed straight into B-fragments (no cross-lane movement) ---
    vs8 pb[2][2];  // [qn][kj]
    #pragma unroll
    for (int qn = 0; qn < 2; ++qn)
      #pragma unroll
      for (int kj = 0; kj < 2; ++kj) {
        u32x4 w;
        w[0] = cvtpk(EXP2(s[2 * kj][qn][0]),     EXP2(s[2 * kj][qn][1]));
        w[1] = cvtpk(EXP2(s[2 * kj][qn][2]),     EXP2(s[2 * kj][qn][3]));
        w[2] = cvtpk(EXP2(s[2 * kj + 1][qn][0]), EXP2(s[2 * kj + 1][qn][1]));
        w[3] = cvtpk(EXP2(s[2 * kj + 1][qn][2]), EXP2(s[2 * kj + 1][qn][3]));
        pb[qn][kj] = __builtin_bit_cast(vs8, w);
      }
    // --- O^T += V^T P ; l += ones^T P ---
    __builtin_amdgcn_s_setprio(1);
    #pragma unroll
    for (int kj = 0; kj < 2; ++kj) {
      #pragma unroll
      for (int mt = 0; mt < 4; ++mt) {
        vs8 vf = *(const vs8*)(sbv + (mt * 2 + kj) * 512 + lane * 8);
        oacc[mt][0] = MFMA(vf, pb[0][kj], oacc[mt][0]);
        oacc[mt][1] = MFMA(vf, pb[1][kj], oacc[mt][1]);
      }
      lacc[0] = MFMA(onesf, pb[0][kj], lacc[0]);
      lacc[1] = MFMA(onesf, pb[1][kj], lacc[1]);
    }
    __builtin_amdgcn_s_setprio(0);
    asm volatile("s_waitcnt vmcnt(0)");  // staged next-chunk loads have landed
    __syncthreads();
  }
  // --- epilogue: n-major ou[(b*NN + q)*HID + h*64 + d], 8B packed stores ---
  const int b = bh >> 3, h = bh & 7;
  float rl2[2] = {1.0f / lacc[0][0], 1.0f / lacc[1][0]};
  const size_t rowbase = (size_t)b * NN;
  #pragma unroll
  for (int mt = 0; mt < 4; ++mt)
    #pragma unroll
    for (int qn = 0; qn < 2; ++qn) {
      unsigned int w0 = cvtpk(oacc[mt][qn][0] * rl2[qn], oacc[mt][qn][1] * rl2[qn]);
      unsigned int w1 = cvtpk(oacc[mt][qn][2] * rl2[qn], oacc[mt][qn][3] * rl2[qn]);
      const int q = qbase + qn * 16 + lr;
      *(unsigned long long*)(&ou[(rowbase + q) * HID + h * 64 + mt * 16 + lg * 4]) =
          ((unsigned long long)w1 << 32) | w0;
    }
}

// ---------- K4: out projection y = w_out @ O + b (LDS-free; ou n-major, L2-served) ----------
__global__ __launch_bounds__(256) void k_out(const unsigned short* __restrict__ ou,
    const unsigned short* __restrict__ wo, const float* __restrict__ bout,
    float* __restrict__ y) {
  const int bo = blockIdx.x & 3;
  const int bn = (blockIdx.x >> 2) & 63;
  const int b  = blockIdx.x >> 8;
  const int o0 = bo * 64, n0 = bn * 64;
  const int tid = threadIdx.x, wave = tid >> 6, lane = tid & 63, lr = lane & 15, lg = lane >> 4;
  const int orow = o0 + wave * 16;
  f4 acc[4] = { {0,0,0,0},{0,0,0,0},{0,0,0,0},{0,0,0,0} };
  const unsigned short* wp = wo + (size_t)(orow + lr) * HID + lg * 8;
  const unsigned short* op = ou + ((size_t)b * NN + n0) * HID + lg * 8;
  #pragma unroll
  for (int c00 = 0; c00 < HID; c00 += 32) {
    vs8 af = *(const vs8*)(wp + c00);
    #pragma unroll
    for (int nc = 0; nc < 4; ++nc) {
      vs8 bf = *(const vs8*)(op + (size_t)(nc * 16 + lr) * HID + c00);
      acc[nc] = MFMA(af, bf, acc[nc]);
    }
  }
  #pragma unroll
  for (int nc = 0; nc < 4; ++nc) {
    const int n = n0 + nc * 16 + lr;
    #pragma unroll
    for (int r = 0; r < 4; ++r)
      y[((size_t)b * C + orow + lg * 4 + r) * NN + n] = acc[nc][r] + bout[orow + lg * 4 + r];
  }
}

extern "C" void kernel_launch(void* const* d_in, const int* in_sizes, int n_in,
                              void* d_out, int out_size, void* d_ws, size_t ws_size,
                              hipStream_t stream) {
  const float* x    = (const float*)d_in[0];
  const float* g    = (const float*)d_in[1];
  const float* wqkv = (const float*)d_in[2];
  const float* wout = (const float*)d_in[3];
  const float* bout = (const float*)d_in[4];
  float* y = (float*)d_out;
  char* ws = (char*)d_ws;
  unsigned short* wg  = (unsigned short*)(ws);                          // 768 KB
  unsigned short* wo  = (unsigned short*)(ws + 786432);                 // 256 KB
  unsigned short* xnb = (unsigned short*)(ws + 1048576);                // 4 MB fragment-major
  unsigned short* qb  = (unsigned short*)(ws + 1048576 + 4194304);      // 8 MB [bh][n][64]
  unsigned short* kb  = (unsigned short*)(ws + 1048576 + 4194304 + 8388608);
  unsigned short* vtb = (unsigned short*)(ws + 1048576 + 4194304 + 2 * 8388608);
  unsigned short* ou  = (unsigned short*)(ws + 1048576 + 4194304 + 3 * 8388608);
  k_prep<<<1536, 256, 0, stream>>>(wqkv, g, wout, wg, wo);
  k_xn<<<128, 256, 0, stream>>>(x, xnb);
  k_qkv<<<768, 256, 0, stream>>>(xnb, wg, qb, kb, vtb);
  k_attn<<<512, 256, 0, stream>>>(qb, kb, vtb, ou);
  k_out<<<512, 256, 0, stream>>>(ou, wo, bout, y);
}

// Round 22
// 120.652 us; speedup vs baseline: 1.0253x; 1.0253x over previous
//
#include <hip/hip_runtime.h>
#include <type_traits>

#define DI __device__ __forceinline__

typedef __attribute__((ext_vector_type(8))) __bf16 vbf8;
typedef __attribute__((ext_vector_type(8))) short  vs8;
typedef __attribute__((ext_vector_type(4))) float  f4;
typedef __attribute__((ext_vector_type(4))) unsigned int u32x4;

static constexpr int BB   = 2;
static constexpr int C    = 256;
static constexpr int NN   = 4096;   // H*W*D
static constexpr int HID  = 512;
static constexpr int QKVR = 1536;

// ---------- bf16 helpers ----------
static DI unsigned short f2bf(float f) {   // round-to-nearest-even
  unsigned int u = __builtin_bit_cast(unsigned int, f);
  u += 0x7fffu + ((u >> 16) & 1u);
  return (unsigned short)(u >> 16);
}
static DI float bf2f(unsigned short u) {
  return __builtin_bit_cast(float, (unsigned int)u << 16);
}
static DI unsigned int cvtpk(float lo, float hi) {  // 2xf32 -> packed bf16 (RNE)
  unsigned int r;
  asm("v_cvt_pk_bf16_f32 %0, %1, %2" : "=v"(r) : "v"(lo), "v"(hi));
  return r;
}
static DI float EXP2(float x) {            // raw v_exp_f32: 2^x, 1 trans op
  float r;
  asm("v_exp_f32 %0, %1" : "=v"(r) : "v"(x));
  return r;
}

// ---------- MFMA wrapper robust to builtin signature (v8bf16 vs v8i16) ----------
template <typename V>
static DI auto mfma_sel(V a, V b, f4 c, int)
    -> decltype(__builtin_amdgcn_mfma_f32_16x16x32_bf16(a, b, c, 0, 0, 0)) {
  return __builtin_amdgcn_mfma_f32_16x16x32_bf16(a, b, c, 0, 0, 0);
}
template <typename V>
static DI f4 mfma_sel(V a, V b, f4 c, long) {
  return __builtin_amdgcn_mfma_f32_16x16x32_bf16(
      __builtin_bit_cast(vs8, a), __builtin_bit_cast(vs8, b), c, 0, 0, 0);
}
static DI f4 MFMA(vs8 a, vs8 b, f4 c) {
  return mfma_sel(__builtin_bit_cast(vbf8, a), __builtin_bit_cast(vbf8, b), c, 0);
}

// ---------- async global->LDS, 16B per lane ----------
static DI void gll16(const unsigned short* g, unsigned short* l) {
  __builtin_amdgcn_global_load_lds(
      (const __attribute__((address_space(1))) unsigned int*)g,
      (__attribute__((address_space(3))) unsigned int*)l, 16, 0, 0);
}

// ---------- K0: cast weights to bf16 (fold g into w_qkv columns) ----------
__global__ void k_prep(const float* __restrict__ wqkv, const float* __restrict__ g,
                       const float* __restrict__ wout,
                       unsigned short* __restrict__ wg, unsigned short* __restrict__ wo) {
  int i = blockIdx.x * 256 + threadIdx.x;
  if (i < QKVR * C) wg[i] = f2bf(wqkv[i] * g[i & (C - 1)]);
  if (i < C * HID)  wo[i] = f2bf(wout[i]);
}

// ---------- K2: QKV projection GEMM (o-tile 256, n-tile 64), norm fused, packed LDS writes ----------
// V stored j-PERMUTED within each 64-block: stored pos p holds original row
// sigma(p) = (p&32) + ((p&7)>>2)*16 + ((p>>3)&3)*4 + (p&3), so k_attn's PV
// B-fragment packs directly from the QK^T C-layout with no cross-lane ops.
__global__ __launch_bounds__(256) void k_qkv(const float* __restrict__ x,
    const unsigned short* __restrict__ wg,
    unsigned short* __restrict__ qo, unsigned short* __restrict__ ko,
    unsigned short* __restrict__ vo) {
  __shared__ unsigned short xs[64 * 264];
  __shared__ float ps[4][64];
  __shared__ float inv[64];
  const int bo = blockIdx.x % 6;
  const int bn = (blockIdx.x / 6) & 63;
  const int b  = blockIdx.x / 384;
  const int o0 = bo * 256, n0 = bn * 64;
  const int tid = threadIdx.x;
  {
    const int nl = tid & 63, cb = tid >> 6;
    const float* xp = x + (size_t)b * C * NN + n0 + nl;
    float s = 0.f;
    #pragma unroll
    for (int k8 = 0; k8 < 8; ++k8) {
      float v[8];
      #pragma unroll
      for (int j = 0; j < 8; ++j) {
        v[j] = xp[(size_t)(cb * 64 + k8 * 8 + j) * NN];
        s += v[j] * v[j];
      }
      u32x4 pk;
      pk[0] = cvtpk(v[0], v[1]); pk[1] = cvtpk(v[2], v[3]);
      pk[2] = cvtpk(v[4], v[5]); pk[3] = cvtpk(v[6], v[7]);
      *(u32x4*)(&xs[nl * 264 + cb * 64 + k8 * 8]) = pk;
    }
    ps[cb][nl] = s;
  }
  __syncthreads();
  if (tid < 64) {
    float t4 = ps[0][tid] + ps[1][tid] + ps[2][tid] + ps[3][tid];
    inv[tid] = 16.0f / fmaxf(sqrtf(t4), 1e-12f);
  }
  __syncthreads();
  const int wave = tid >> 6, lane = tid & 63, lr = lane & 15, lg = lane >> 4;
  const int orow = o0 + wave * 64;          // 64 rows per wave = 4 sub-tiles of 16
  f4 acc[4][4];
  #pragma unroll
  for (int om = 0; om < 4; ++om)
    #pragma unroll
    for (int nc = 0; nc < 4; ++nc) acc[om][nc] = f4{0.f, 0.f, 0.f, 0.f};
  const unsigned short* wpb = wg + (size_t)(orow + lr) * C + lg * 8;
  #pragma unroll
  for (int c0 = 0; c0 < C; c0 += 32) {
    vs8 bfv[4];
    #pragma unroll
    for (int nc = 0; nc < 4; ++nc)
      bfv[nc] = *(const vs8*)(&xs[(nc * 16 + lr) * 264 + c0 + lg * 8]);
    #pragma unroll
    for (int om = 0; om < 4; ++om) {
      vs8 af = *(const vs8*)(wpb + (size_t)om * 16 * C + c0);
      #pragma unroll
      for (int nc = 0; nc < 4; ++nc) acc[om][nc] = MFMA(af, bfv[nc], acc[om][nc]);
    }
  }
  #pragma unroll
  for (int om = 0; om < 4; ++om) {
    const int om_row = orow + om * 16;
    const int otype = om_row >> 9;        // 0=q 1=k 2=v
    const int head  = (om_row >> 6) & 7;
    const int bh    = b * 8 + head;
    const int dbase = (om_row & 63) + lg * 4;
    #pragma unroll
    for (int nc = 0; nc < 4; ++nc) {
      const int n = n0 + nc * 16 + lr;
      float s = inv[nc * 16 + lr];
      if (otype == 0) s *= 0.125f * 1.44269504088896f; // fold dh^-0.5 and log2(e)
      if (otype < 2) {                    // q,k: [bh][n][64]
        unsigned short* dst = (otype == 0 ? qo : ko) + ((size_t)bh * NN + n) * 64 + dbase;
        unsigned int lo = cvtpk(acc[om][nc][0] * s, acc[om][nc][1] * s);
        unsigned int hi = cvtpk(acc[om][nc][2] * s, acc[om][nc][3] * s);
        *(unsigned long long*)dst = ((unsigned long long)hi << 32) | lo;
      } else {                            // v transposed + j-permuted: [bh][64][n_perm]
        // o = nc*16+lr; stored pos = kj*32 + (lr>>2)*8 + (nc&1)*4 + (lr&3), kj=nc>>1
        const int np = n0 + ((nc >> 1) << 5) + ((lr >> 2) << 3) + ((nc & 1) << 2) + (lr & 3);
        #pragma unroll
        for (int r = 0; r < 4; ++r)
          vo[((size_t)bh * 64 + dbase + r) * NN + np] = f2bf(acc[om][nc][r] * s);
      }
    }
  }
}

// ---------- K3: flash attention, v13 body (permuted-V direct pb packing) ----------
// 4 waves/block, 32 q/wave, KVBLK=64, K+V double-buffered in LDS (32 KB/block).
// No max-tracking (S hard-bounded). l via ones-row MFMA.
// __launch_bounds__(256,4): 64-reg budget (56 measured). NEVER min-waves 8 (32-reg spill).
template <int SPLITS>
__global__ __launch_bounds__(256, 4) void k_attn(const unsigned short* __restrict__ qq,
    const unsigned short* __restrict__ kk, const unsigned short* __restrict__ vv,
    unsigned short* __restrict__ ou, float* __restrict__ st) {
  __shared__ unsigned short stg[2][8192];      // [buf][ K 8 groups*512 | V 8 groups*512 ]
  constexpr int NB  = 512 * SPLITS;
  constexpr int CPX = NB / 8;
  constexpr int JCH = NN / SPLITS / 64;
  const int bid = blockIdx.x;
  const int swz = (bid & 7) * CPX + (bid >> 3); // XCD-aware, bijective (NB % 8 == 0)
  const int qt   = swz & 31;
  const int rest = swz >> 5;
  const int sp   = (SPLITS > 1) ? (rest % SPLITS) : 0;
  const int bh   = (SPLITS > 1) ? (rest / SPLITS) : rest;
  const int js   = sp * (NN / SPLITS);
  const int tid = threadIdx.x, wave = tid >> 6, lane = tid & 63;
  const int lr = lane & 15, lg = lane >> 4;
  const int qbase = qt * 128 + wave * 32;
  const unsigned short* kb = kk + (size_t)bh * NN * 64;   // [n][64]
  const unsigned short* vb = vv + (size_t)bh * 64 * NN;   // [64][n_perm]
  vs8 qf[2][2];
  #pragma unroll
  for (int qn = 0; qn < 2; ++qn)
    #pragma unroll
    for (int kd = 0; kd < 2; ++kd)
      qf[qn][kd] = *(const vs8*)(qq + ((size_t)bh * NN + qbase + qn * 16 + lr) * 64 + kd * 32 + lg * 8);
  const vs8 onesf = {0x3F80, 0x3F80, 0x3F80, 0x3F80, 0x3F80, 0x3F80, 0x3F80, 0x3F80};
  const f4 zero4 = {0.f, 0.f, 0.f, 0.f};
  f4 oacc[4][2] = { { {0,0,0,0},{0,0,0,0} }, { {0,0,0,0},{0,0,0,0} },
                    { {0,0,0,0},{0,0,0,0} }, { {0,0,0,0},{0,0,0,0} } };
  f4 lacc[2] = { {0,0,0,0}, {0,0,0,0} };

  auto stage = [&](int j0, int buf) {
    #pragma unroll
    for (int p = 0; p < 2; ++p) {
      const int g  = wave * 2 + p;
      const int jt = g >> 1, kd = g & 1;     // K group
      gll16(kb + (size_t)(j0 + jt * 16 + lr) * 64 + kd * 32 + lg * 8,
            &stg[buf][g * 512]);
      const int dt = g >> 1, kj = g & 1;     // V group (global already j-permuted)
      gll16(vb + (size_t)(dt * 16 + lr) * NN + j0 + kj * 32 + lg * 8,
            &stg[buf][4096 + g * 512]);
    }
  };

  stage(js, 0);
  asm volatile("s_waitcnt vmcnt(0)");
  __syncthreads();

  for (int t = 0; t < JCH; ++t) {
    const int cur = t & 1;
    if (t + 1 < JCH) stage(js + (t + 1) * 64, cur ^ 1);
    const unsigned short* sbk = stg[cur];
    const unsigned short* sbv = stg[cur] + 4096;
    // --- S^T = K Q^T : first MFMA uses loop-invariant zero C ---
    f4 s[4][2];
    __builtin_amdgcn_s_setprio(1);
    #pragma unroll
    for (int jt = 0; jt < 4; ++jt) {
      vs8 k0 = *(const vs8*)(sbk + (jt * 2 + 0) * 512 + lane * 8);
      vs8 k1 = *(const vs8*)(sbk + (jt * 2 + 1) * 512 + lane * 8);
      #pragma unroll
      for (int qn = 0; qn < 2; ++qn) {
        s[jt][qn] = MFMA(k0, qf[qn][0], zero4);
        s[jt][qn] = MFMA(k1, qf[qn][1], s[jt][qn]);
      }
    }
    __builtin_amdgcn_s_setprio(0);
    // --- P = 2^S, packed straight into B-fragments (no cross-lane movement) ---
    vs8 pb[2][2];  // [qn][kj]
    #pragma unroll
    for (int qn = 0; qn < 2; ++qn)
      #pragma unroll
      for (int kj = 0; kj < 2; ++kj) {
        u32x4 w;
        w[0] = cvtpk(EXP2(s[2 * kj][qn][0]),     EXP2(s[2 * kj][qn][1]));
        w[1] = cvtpk(EXP2(s[2 * kj][qn][2]),     EXP2(s[2 * kj][qn][3]));
        w[2] = cvtpk(EXP2(s[2 * kj + 1][qn][0]), EXP2(s[2 * kj + 1][qn][1]));
        w[3] = cvtpk(EXP2(s[2 * kj + 1][qn][2]), EXP2(s[2 * kj + 1][qn][3]));
        pb[qn][kj] = __builtin_bit_cast(vs8, w);
      }
    // --- O^T += V^T P ; l += ones^T P ---
    __builtin_amdgcn_s_setprio(1);
    #pragma unroll
    for (int kj = 0; kj < 2; ++kj) {
      #pragma unroll
      for (int mt = 0; mt < 4; ++mt) {
        vs8 vf = *(const vs8*)(sbv + (mt * 2 + kj) * 512 + lane * 8);
        oacc[mt][0] = MFMA(vf, pb[0][kj], oacc[mt][0]);
        oacc[mt][1] = MFMA(vf, pb[1][kj], oacc[mt][1]);
      }
      lacc[0] = MFMA(onesf, pb[0][kj], lacc[0]);
      lacc[1] = MFMA(onesf, pb[1][kj], lacc[1]);
    }
    __builtin_amdgcn_s_setprio(0);
    asm volatile("s_waitcnt vmcnt(0)");  // staged next-chunk loads have landed
    __syncthreads();
  }
  // --- epilogue: n-major ou[((sp*BB+b)*NN + q)*HID + h*64 + d], 8B packed stores ---
  const int b = bh >> 3, h = bh & 7;
  float rl2[2] = {1.f, 1.f};
  if (SPLITS == 1) { rl2[0] = 1.0f / lacc[0][0]; rl2[1] = 1.0f / lacc[1][0]; }
  const size_t rowbase = (size_t)((SPLITS > 1 ? sp * BB : 0) + b) * NN;
  #pragma unroll
  for (int mt = 0; mt < 4; ++mt)
    #pragma unroll
    for (int qn = 0; qn < 2; ++qn) {
      unsigned int w0 = cvtpk(oacc[mt][qn][0] * rl2[qn], oacc[mt][qn][1] * rl2[qn]);
      unsigned int w1 = cvtpk(oacc[mt][qn][2] * rl2[qn], oacc[mt][qn][3] * rl2[qn]);
      const int q = qbase + qn * 16 + lr;
      *(unsigned long long*)(&ou[(rowbase + q) * HID + h * 64 + mt * 16 + lg * 4]) =
          ((unsigned long long)w1 << 32) | w0;
    }
  if (SPLITS > 1 && lg == 0) {
    #pragma unroll
    for (int qn = 0; qn < 2; ++qn)
      st[(size_t)(sp * 16 + bh) * NN + qbase + qn * 16 + lr] = lacc[qn][0];
  }
}

// ---------- K4: out projection y = w_out @ O + b ----------
// SPLITS==1: LDS-free — B-fragments read per-lane straight from n-major ou (L2-served,
// 4x reuse across bo-blocks). No barriers, no staging.
template <int SPLITS>
__global__ __launch_bounds__(256) void k_out(const unsigned short* __restrict__ ou,
    const float* __restrict__ st, const unsigned short* __restrict__ wo,
    const float* __restrict__ bout, float* __restrict__ y) {
  const int bo = blockIdx.x & 3;
  const int bn = (blockIdx.x >> 2) & 63;
  const int b  = blockIdx.x >> 8;
  const int o0 = bo * 64, n0 = bn * 64;
  const int tid = threadIdx.x, wave = tid >> 6, lane = tid & 63, lr = lane & 15, lg = lane >> 4;
  const int orow = o0 + wave * 16;
  f4 acc[4] = { {0,0,0,0},{0,0,0,0},{0,0,0,0},{0,0,0,0} };
  if constexpr (SPLITS == 1) {
    const unsigned short* wp = wo + (size_t)(orow + lr) * HID + lg * 8;
    const unsigned short* op = ou + ((size_t)b * NN + n0) * HID + lg * 8;
    #pragma unroll
    for (int c00 = 0; c00 < HID; c00 += 32) {
      vs8 af = *(const vs8*)(wp + c00);
      #pragma unroll
      for (int nc = 0; nc < 4; ++nc) {
        vs8 bf = *(const vs8*)(op + (size_t)(nc * 16 + lr) * HID + c00);
        acc[nc] = MFMA(af, bf, acc[nc]);
      }
    }
  } else {
    __shared__ unsigned short os[64 * 136];
    for (int c0 = 0; c0 < HID; c0 += 128) {
      __syncthreads();
      {
        const int nl = tid & 63, cb = tid >> 6;
        const int n = n0 + nl;
        const int h  = (c0 + cb * 32) >> 6;
        const int bh = b * 8 + h;
        float lsum = 0.f;
        #pragma unroll
        for (int s = 0; s < SPLITS; ++s) lsum += st[(size_t)(s * 16 + bh) * NN + n];
        const float rl = 1.0f / lsum;
        #pragma unroll
        for (int t = 0; t < 4; ++t) {
          const int cc = cb * 32 + t * 8;
          float a[8] = {0,0,0,0,0,0,0,0};
          #pragma unroll
          for (int s = 0; s < SPLITS; ++s) {
            vs8 v = *(const vs8*)(&ou[((size_t)(s * BB + b) * NN + n) * HID + c0 + cc]);
            #pragma unroll
            for (int j = 0; j < 8; ++j) a[j] += bf2f((unsigned short)v[j]);
          }
          u32x4 pk;
          pk[0] = cvtpk(a[0] * rl, a[1] * rl);
          pk[1] = cvtpk(a[2] * rl, a[3] * rl);
          pk[2] = cvtpk(a[4] * rl, a[5] * rl);
          pk[3] = cvtpk(a[6] * rl, a[7] * rl);
          *(u32x4*)(&os[nl * 136 + cc]) = pk;
        }
      }
      __syncthreads();
      const unsigned short* wp = wo + (size_t)(orow + lr) * HID + c0 + lg * 8;
      #pragma unroll
      for (int cc0 = 0; cc0 < 128; cc0 += 32) {
        vs8 af = *(const vs8*)(wp + cc0);
        #pragma unroll
        for (int nc = 0; nc < 4; ++nc) {
          vs8 bf = *(const vs8*)(&os[(nc * 16 + lr) * 136 + cc0 + lg * 8]);
          acc[nc] = MFMA(af, bf, acc[nc]);
        }
      }
    }
  }
  #pragma unroll
  for (int nc = 0; nc < 4; ++nc) {
    const int n = n0 + nc * 16 + lr;
    #pragma unroll
    for (int r = 0; r < 4; ++r)
      y[((size_t)b * C + orow + lg * 4 + r) * NN + n] = acc[nc][r] + bout[orow + lg * 4 + r];
  }
}

extern "C" void kernel_launch(void* const* d_in, const int* in_sizes, int n_in,
                              void* d_out, int out_size, void* d_ws, size_t ws_size,
                              hipStream_t stream) {
  const float* x    = (const float*)d_in[0];
  const float* g    = (const float*)d_in[1];
  const float* wqkv = (const float*)d_in[2];
  const float* wout = (const float*)d_in[3];
  const float* bout = (const float*)d_in[4];
  float* y = (float*)d_out;
  char* ws = (char*)d_ws;
  unsigned short* wg  = (unsigned short*)(ws);                          // 768 KB
  unsigned short* wo  = (unsigned short*)(ws + 786432);                 // 256 KB
  unsigned short* qb  = (unsigned short*)(ws + 1048576);                // 8 MB [bh][n][64]
  unsigned short* kb  = (unsigned short*)(ws + 1048576 + 8388608);      // 8 MB [bh][n][64]
  unsigned short* vtb = (unsigned short*)(ws + 1048576 + 2 * 8388608);  // 8 MB [bh][64][n_perm]
  unsigned short* ou  = (unsigned short*)(ws + 1048576 + 3 * 8388608);  // 8 MB, n-major [b][q][hid]
  k_prep<<<1536, 256, 0, stream>>>(wqkv, g, wout, wg, wo);
  k_qkv<<<768, 256, 0, stream>>>(x, wg, qb, kb, vtb);
  k_attn<1><<<512, 256, 0, stream>>>(qb, kb, vtb, ou, nullptr);
  k_out<1><<<512, 256, 0, stream>>>(ou, nullptr, wo, bout, y);
}